// Round 1
// baseline (517.839 us; speedup 1.0000x reference)
//
#include <hip/hip_runtime.h>
#include <hip/hip_bf16.h>

typedef __bf16 v8bf __attribute__((ext_vector_type(8)));
typedef float  v4f  __attribute__((ext_vector_type(4)));

namespace {
constexpr int C    = 256;
constexpr int L    = 8192;
constexpr int LT   = 64;    // l-tile per block
constexpr int LDXs = 264;   // bf16 row stride (256 + 8 pad)
constexpr int NBLK = 512;
constexpr int TPB_TILES = 8;  // 4096 tiles total / 512 blocks
}

// block = 512 threads (8 waves). Wave w owns output channels o in [32w, 32w+32)
// (ni=2 -> wf is 64 VGPRs instead of 128 -> 4 waves/SIMD occupancy).
// MFMA 16x16x32 bf16: A = x^T tile (m=l), B = BN-folded W (n=o).
// Squash norm computed from registers via shfl butterfly + 4KB partial buffer;
// stores go straight from registers (no ys LDS round-trip).
// x staging uses an XOR swizzle (granule ^ (row>>2)&3) -> conflict-free b64 writes.
__global__ __launch_bounds__(512, 4)
void caps_fused(const float* __restrict__ xg, const float* __restrict__ Wg,
                const float* __restrict__ bg, const float* __restrict__ gg,
                const float* __restrict__ betag, const float* __restrict__ mg,
                const float* __restrict__ vg, float* __restrict__ outg)
{
    __shared__ unsigned short xs[LT * LDXs];   // 33792 B  bf16 x^T tile [l][c] (swizzled)
    __shared__ float pbuf[2][LT][8];           //  4096 B  per-(l,wave) |y|^2 partials

    const int t    = threadIdx.x;
    const int w    = t >> 6;
    const int ln   = t & 63;
    const int ln15 = ln & 15;
    const int lhi  = ln >> 4;

    // ---- fold BN into W (bf16 fragments) and bias; persistent in registers ----
    v8bf  wf[8][2];     // [kb][ni] : B-frag lane layout n=ln15, k=8*lhi+j
    float bias_f[2];
#pragma unroll
    for (int ni = 0; ni < 2; ++ni) {
        const int o = w * 32 + ni * 16 + ln15;
        const float inv = gg[o] * rsqrtf(vg[o] + 1e-5f);
        bias_f[ni] = bg[o] * inv + betag[o] - mg[o] * inv;
#pragma unroll
        for (int kb = 0; kb < 8; ++kb) {
            const float* wp = Wg + o * C + kb * 32 + lhi * 8;
            const float4 wa = *(const float4*)wp;
            const float4 wb = *(const float4*)(wp + 4);
            union { v8bf v; __hip_bfloat16 h[8]; } fu;
            fu.h[0] = __float2bfloat16(wa.x * inv);
            fu.h[1] = __float2bfloat16(wa.y * inv);
            fu.h[2] = __float2bfloat16(wa.z * inv);
            fu.h[3] = __float2bfloat16(wa.w * inv);
            fu.h[4] = __float2bfloat16(wb.x * inv);
            fu.h[5] = __float2bfloat16(wb.y * inv);
            fu.h[6] = __float2bfloat16(wb.z * inv);
            fu.h[7] = __float2bfloat16(wb.w * inv);
            wf[kb][ni] = fu.v;
        }
    }

    const int lq  = (t & 15) * 4;       // base l row (4 rows per thread) for staging
    const int swz = t & 3;              // == ((row>>2)&3) for rows lq..lq+3
    const int rsw = (lhi ^ (ln15 >> 2)) << 3;   // read-side swizzled column offset

    for (int ti = 0; ti < TPB_TILES; ++ti) {
        const int tile = blockIdx.x * TPB_TILES + ti;
        const int b    = tile >> 7;          // 128 l-tiles per batch
        const int l0   = (tile & 127) << 6;
        const float* xb = xg + (size_t)b * C * L + l0;
        float*       ob = outg + ((size_t)b * L + l0) * C;

        // ---- stage x tile -> LDS, transposed to [l][c] bf16, XOR-swizzled ----
        // prev tile's xs readers (K-loop) finished before prev post-K barrier.
        {
            const int cgi = t >> 4;        // 0..31
#pragma unroll
            for (int it = 0; it < 2; ++it) {
                const int c0 = cgi * 4 + it * 128;
                float4 f[4];
#pragma unroll
                for (int j = 0; j < 4; ++j)
                    f[j] = *(const float4*)(xb + (size_t)(c0 + j) * L + lq);
                const int cs = (((c0 >> 3) ^ swz) << 3) + (c0 & 7);
#pragma unroll
                for (int i = 0; i < 4; ++i) {
                    union { unsigned long long u; __hip_bfloat16 h[4]; } p;
                    p.h[0] = __float2bfloat16(((const float*)&f[0])[i]);
                    p.h[1] = __float2bfloat16(((const float*)&f[1])[i]);
                    p.h[2] = __float2bfloat16(((const float*)&f[2])[i]);
                    p.h[3] = __float2bfloat16(((const float*)&f[3])[i]);
                    *(unsigned long long*)&xs[(lq + i) * LDXs + cs] = p.u;
                }
            }
        }
        __syncthreads();

        // ---- K-loop: 8 steps of K=32, 8 MFMA per wave per step ----
        v4f acc[4][2];
        const v4f vzero = {0.f, 0.f, 0.f, 0.f};
#pragma unroll
        for (int mi = 0; mi < 4; ++mi) {
            acc[mi][0] = vzero;
            acc[mi][1] = vzero;
        }

#pragma unroll
        for (int kb = 0; kb < 8; ++kb) {
            v8bf a[4];
#pragma unroll
            for (int mi = 0; mi < 4; ++mi)
                a[mi] = *(const v8bf*)&xs[(mi * 16 + ln15) * LDXs + kb * 32 + rsw];
#pragma unroll
            for (int mi = 0; mi < 4; ++mi) {
                acc[mi][0] = __builtin_amdgcn_mfma_f32_16x16x32_bf16(
                    a[mi], wf[kb][0], acc[mi][0], 0, 0, 0);
                acc[mi][1] = __builtin_amdgcn_mfma_f32_16x16x32_bf16(
                    a[mi], wf[kb][1], acc[mi][1], 0, 0, 0);
            }
        }

        // ---- bias + per-row |y|^2 partials (butterfly over the 16-lane group) ----
        float* pb = &pbuf[ti & 1][0][0];
#pragma unroll
        for (int mi = 0; mi < 4; ++mi) {
#pragma unroll
            for (int r = 0; r < 4; ++r) {
                acc[mi][0][r] += bias_f[0];
                acc[mi][1][r] += bias_f[1];
                float s = acc[mi][0][r] * acc[mi][0][r]
                        + acc[mi][1][r] * acc[mi][1][r];
                s += __shfl_xor(s, 1);
                s += __shfl_xor(s, 2);
                s += __shfl_xor(s, 4);
                s += __shfl_xor(s, 8);
                if (ln15 == r)
                    pb[(mi * 16 + lhi * 4 + r) * 8 + w] = s;
            }
        }
        __syncthreads();   // pbuf visible; also fences this tile's xs reads

        // ---- scale + store straight from registers ----
        // per (mi,r): 64 lanes cover 4 rows x 16 cols -> 64B segments, full sectors
#pragma unroll
        for (int mi = 0; mi < 4; ++mi) {
#pragma unroll
            for (int r = 0; r < 4; ++r) {
                const int l = mi * 16 + lhi * 4 + r;
                const float4 pa = *(const float4*)&pb[l * 8];
                const float4 pc = *(const float4*)&pb[l * 8 + 4];
                const float n2 = pa.x + pa.y + pa.z + pa.w
                               + pc.x + pc.y + pc.z + pc.w;
                const float sc = n2 / ((1.f + n2) * (sqrtf(n2) + 1e-8f));
                ob[(size_t)l * C + w * 32 + ln15]      = acc[mi][0][r] * sc;
                ob[(size_t)l * C + w * 32 + 16 + ln15] = acc[mi][1][r] * sc;
            }
        }
    }
}

extern "C" void kernel_launch(void* const* d_in, const int* in_sizes, int n_in,
                              void* d_out, int out_size, void* d_ws, size_t ws_size,
                              hipStream_t stream)
{
    const float* x     = (const float*)d_in[0];
    const float* W     = (const float*)d_in[1];
    const float* b     = (const float*)d_in[2];
    const float* gamma = (const float*)d_in[3];
    const float* beta  = (const float*)d_in[4];
    const float* mean  = (const float*)d_in[5];
    const float* var   = (const float*)d_in[6];
    float* out = (float*)d_out;

    hipLaunchKernelGGL(caps_fused, dim3(NBLK), dim3(512), 0, stream,
                       x, W, b, gamma, beta, mean, var, out);
}